// Round 13
// baseline (26686.163 us; speedup 1.0000x reference)
//
#include <hip/hip_runtime.h>
#include <hip/hip_cooperative_groups.h>
#include <math.h>

namespace cg = cooperative_groups;

// ---- problem dims ----
#define TN 64
#define BN 32
#define EPSF 1e-6f

// ---- workspace layout (floats): full H/RV history for deferred out-GEMM ----
constexpr long OFF_H     = 0;                       // 65 * 32*1024
constexpr long OFF_RV    = OFF_H    + 65L*32768;    // 65 * 32*256
constexpr long OFF_S     = OFF_RV   + 65L*8192;     // 32768
constexpr long OFF_RW    = OFF_S    + 32768;        // B*N*HD = 16384
constexpr long OFF_WW    = OFF_RW   + 16384;        // B*N
constexpr long OFF_U     = OFF_WW   + 4096;
constexpr long OFF_P     = OFF_U    + 4096;
constexpr long OFF_MEM   = OFF_P    + 4096;         // B*N*WD = 262144
constexpr long OFF_LINKS = OFF_MEM  + 262144;       // B*N*N = 524288
constexpr long OFF_PROJ  = OFF_LINKS+ 524288;       // B*512 (471 used)
constexpr long OFF_SRC   = OFF_PROJ + 16384;        // 2048 ints
// total ≈ 14.1 MB (proven footprint)

__device__ __forceinline__ float sigm(float x) { return 1.f / (1.f + expf(-x)); }
__device__ __forceinline__ float oneplus_(float x) {
  return 1.f + fmaxf(x, 0.f) + log1pf(expf(-fabsf(x)));
}

// ===== src width auto-detect + decode to int32 (validated round 6) =========
__global__ void src_decode(const void* __restrict__ src_raw, float* __restrict__ ws) {
  __shared__ int is64_s;
  if (threadIdx.x == 0) is64_s = 1;
  __syncthreads();
  const long long* s64 = (const long long*)src_raw;
  for (int i = threadIdx.x; i < 1024; i += 256) {
    long long v = s64[i];
    if (v < 0 || v >= 32000) is64_s = 0;
  }
  __syncthreads();
  int* dst = (int*)(ws + OFF_SRC);
  if (is64_s) {
    for (int i = threadIdx.x; i < 2048; i += 256) dst[i] = (int)s64[i];
  } else {
    const int* s32 = (const int*)src_raw;
    for (int i = threadIdx.x; i < 2048; i += 256) dst[i] = s32[i];
  }
}

// ================= init: H slot0, RV slot0, state; U=EPS ====================
__global__ void init_kernel(float* ws) {
  long i0 = (long)blockIdx.x * blockDim.x + threadIdx.x;
  long stride = (long)gridDim.x * blockDim.x;
  for (long x = i0; x < 32768; x += stride) ws[OFF_H + x] = 0.f;
  for (long x = i0; x < 8192;  x += stride) ws[OFF_RV + x] = 0.f;
  const long zlen = OFF_PROJ - OFF_S;
  for (long x = i0; x < zlen; x += stride) {
    long g = OFF_S + x;
    ws[g] = (g >= OFF_U && g < OFF_U + 4096) ? EPSF : 0.f;
  }
}

// ===== param pack for the persistent kernel =====
struct PA {
  const float *emb, *W_ih, *W_hh, *b_ih, *b_hh;
  const float *rk_w, *rk_b, *rs_w, *rs_b, *fg_w, *fg_b, *rm_w, *rm_b;
  const float *wk_w, *wk_b, *ws_w, *ws_b, *ev_w, *ev_b, *wv_w, *wv_b;
  const float *ag_w, *ag_b, *wg_w, *wg_b;
  float* ws;
};

// ===== gates body (r7 exact): 128 blocks x 256 thr; sm = xl[32*260] ========
__device__ void gates_body(const PA& p, int t, float* xl) {
  float* ws = p.ws;
  int tid = threadIdx.x;
  int b = tid & 31, jg = tid >> 5;
  int j = blockIdx.x * 8 + jg;
  const int* src = (const int*)(ws + OFF_SRC);
  float acc0 = 0.f, acc1 = 0.f, acc2 = 0.f, acc3 = 0.f;
  for (int c = 0; c < 7; ++c) {
    __syncthreads();
#pragma unroll
    for (int q = 0; q < 32; ++q) {
      int i2 = q * 256 + tid;
      int bb = i2 >> 8, kk = i2 & 255;
      float v;
      if (c < 2)       v = p.emb[(long)src[t * 32 + bb] * 512 + c * 256 + kk];
      else if (c == 2) v = ws[OFF_RV + (long)t * 8192 + bb * 256 + kk];
      else             v = ws[OFF_H + (long)t * 32768 + bb * 1024 + (c - 3) * 256 + kk];
      xl[bb * 260 + kk] = v;
    }
    __syncthreads();
    const float* xp = &xl[b * 260];
    const float *w0, *w1, *w2, *w3;
    if (c < 3) {
      w0 = p.W_ih + (long)j * 768 + c * 256;
      w1 = p.W_ih + (long)(1024 + j) * 768 + c * 256;
      w2 = p.W_ih + (long)(2048 + j) * 768 + c * 256;
      w3 = p.W_ih + (long)(3072 + j) * 768 + c * 256;
    } else {
      w0 = p.W_hh + (long)j * 1024 + (c - 3) * 256;
      w1 = p.W_hh + (long)(1024 + j) * 1024 + (c - 3) * 256;
      w2 = p.W_hh + (long)(2048 + j) * 1024 + (c - 3) * 256;
      w3 = p.W_hh + (long)(3072 + j) * 1024 + (c - 3) * 256;
    }
#pragma unroll 4
    for (int k = 0; k < 256; k += 4) {
      float4 xv = *(const float4*)(xp + k);
      float4 a = *(const float4*)(w0 + k);
      float4 bb4 = *(const float4*)(w1 + k);
      float4 cc4 = *(const float4*)(w2 + k);
      float4 dd4 = *(const float4*)(w3 + k);
      acc0 += xv.x * a.x + xv.y * a.y + xv.z * a.z + xv.w * a.w;
      acc1 += xv.x * bb4.x + xv.y * bb4.y + xv.z * bb4.z + xv.w * bb4.w;
      acc2 += xv.x * cc4.x + xv.y * cc4.y + xv.z * cc4.z + xv.w * cc4.w;
      acc3 += xv.x * dd4.x + xv.y * dd4.y + xv.z * dd4.z + xv.w * dd4.w;
    }
  }
  float gi = acc0 + p.b_ih[j]        + p.b_hh[j];
  float gf = acc1 + p.b_ih[1024 + j] + p.b_hh[1024 + j];
  float gg = acc2 + p.b_ih[2048 + j] + p.b_hh[2048 + j];
  float go = acc3 + p.b_ih[3072 + j] + p.b_hh[3072 + j];
  long si = (long)b * 1024 + j;
  float sv = sigm(gf) * ws[OFF_S + si] + sigm(gi) * tanhf(gg);
  ws[OFF_S + si] = sv;
  ws[OFF_H + (long)(t + 1) * 32768 + si] = sigm(go) * tanhf(sv);
}

// ===== proj body (r11 exact): blocks 0..119; sm = h_s[8][1032] =============
__device__ void proj_body(const PA& p, int t, float* h_s) {
  float* ws = p.ws;
  int blk = blockIdx.x;
  int obase = (blk % 30) * 16;
  int bbase = (blk / 30) * 8;
  int tid = threadIdx.x;
  for (int q = 0; q < 32; ++q) {
    int idx = q * 256 + tid;          // 0..8191
    int bb = idx >> 10, kk = idx & 1023;
    h_s[bb * 1032 + kk] = ws[OFF_H + (long)(t + 1) * 32768 + (long)(bbase + bb) * 1024 + kk];
  }
  __syncthreads();
  int wv = tid >> 6, lane = tid & 63;
  for (int oi = wv; oi < 16; oi += 4) {
    int o = obase + oi;
    if (o >= 471) continue;   // wave-uniform
    const float* w;
    float bias;
    if (o < 256)      { int wi = o >> 2, hh = o & 3; w = p.rk_w + (long)(hh * 64 + wi) * 1024; bias = p.rk_b[hh * 64 + wi]; }
    else if (o < 260) { int q = o - 256; w = p.rs_w + (long)q * 1024; bias = p.rs_b[q]; }
    else if (o < 264) { int q = o - 260; w = p.fg_w + (long)q * 1024; bias = p.fg_b[q]; }
    else if (o < 276) { int q = o - 264, m = q >> 2, hh = q & 3; w = p.rm_w + (long)(hh * 3 + m) * 1024; bias = p.rm_b[hh * 3 + m]; }
    else if (o < 340) { int q = o - 276; w = p.wk_w + (long)q * 1024; bias = p.wk_b[q]; }
    else if (o == 340){ w = p.ws_w; bias = p.ws_b[0]; }
    else if (o < 405) { int q = o - 341; w = p.ev_w + (long)q * 1024; bias = p.ev_b[q]; }
    else if (o < 469) { int q = o - 405; w = p.wv_w + (long)q * 1024; bias = p.wv_b[q]; }
    else if (o == 469){ w = p.ag_w; bias = p.ag_b[0]; }
    else              { w = p.wg_w; bias = p.wg_b[0]; }
    float wreg[16];
#pragma unroll
    for (int i = 0; i < 16; ++i) wreg[i] = w[lane + 64 * i];
#pragma unroll
    for (int bb = 0; bb < 8; ++bb) {
      float s = 0.f;
#pragma unroll
      for (int i = 0; i < 16; ++i) s += h_s[bb * 1032 + lane + 64 * i] * wreg[i];
#pragma unroll
      for (int off = 32; off; off >>= 1) s += __shfl_xor(s, off);
      if (lane == 0) ws[OFF_PROJ + (long)(bbase + bb) * 512 + o] = s + bias;
    }
  }
}

// ===== reductions over 256 threads =====
__device__ __forceinline__ float blk_max256(float v, float* red, int tid) {
  red[tid] = v; __syncthreads();
#pragma unroll
  for (int s = 128; s > 0; s >>= 1) { if (tid < s) red[tid] = fmaxf(red[tid], red[tid + s]); __syncthreads(); }
  float r = red[0]; __syncthreads();
  return r;
}
__device__ __forceinline__ float blk_sum256(float v, float* red, int tid) {
  red[tid] = v; __syncthreads();
#pragma unroll
  for (int s = 128; s > 0; s >>= 1) { if (tid < s) red[tid] += red[tid + s]; __syncthreads(); }
  float r = red[0]; __syncthreads();
  return r;
}

// ===== memAB body (r12 exact): blocks 0..31; sm layout 29120 floats ========
__device__ void memAB_body(const PA& p, int t, float* sm) {
  float* ws = p.ws;
  float* mem_s = sm;               // [128][65]
  float* lk_s  = sm + 8320;        // [128][129]
  float* red   = sm + 24832;       // 256
  float* su    = sm + 25088;       // 128
  float* lg    = sm + 25216;       // 128
  float* wwl   = sm + 25344;       // 128
  float* pl    = sm + 25472;       // 128
  float* kwl   = sm + 25600;       // 64
  float* knl   = sm + 25664;       // 64
  float* dl    = sm + 25728;       // 64
  float* kl    = sm + 25792;       // 256
  float* rwold = sm + 26048;       // 512
  float* rwnew = sm + 26560;       // 512
  float* fpart = sm + 27072;       // 1024
  float* bpart = sm + 28096;       // 1024
  int b = blockIdx.x, tid = threadIdx.x;
  int n = tid & 127, half = tid >> 7;
  const float* pj = ws + OFF_PROJ + b * 512;
  float* u    = ws + OFF_U  + b * 128;
  float* wwp  = ws + OFF_WW + b * 128;
  float* pp   = ws + OFF_P  + b * 128;
  float* rwp  = ws + OFF_RW + b * 512;
  float* memp = ws + OFF_MEM + (long)b * 8192;
  float* lk   = ws + OFF_LINKS + (long)b * 16384;

  for (int i = tid; i < 8192; i += 256) mem_s[(i >> 6) * 65 + (i & 63)] = memp[i];
  for (int i = tid; i < 16384; i += 256) lk_s[(i >> 7) * 129 + (i & 127)] = lk[i];

  if (half == 0) {
    float fg0 = sigm(pj[260]), fg1 = sigm(pj[261]), fg2 = sigm(pj[262]), fg3 = sigm(pj[263]);
    float r0 = rwp[n * 4], r1 = rwp[n * 4 + 1], r2 = rwp[n * 4 + 2], r3 = rwp[n * 4 + 3];
    rwold[n * 4] = r0; rwold[n * 4 + 1] = r1; rwold[n * 4 + 2] = r2; rwold[n * 4 + 3] = r3;
    float psi = expf(logf(1.f - fg0 * r0) + logf(1.f - fg1 * r1) +
                     logf(1.f - fg2 * r2) + logf(1.f - fg3 * r3));
    float uu = u[n], wwo = wwp[n];
    uu = (uu + wwo - uu * wwo) * psi;
    u[n] = uu;
    su[n] = uu;
  }
  if (tid < 64) {
    kwl[tid] = pj[276 + tid];
    dl[tid] = sigm(pj[405 + tid]) - sigm(pj[341 + tid]);  // writev - erase
  }
  if (tid >= 128 && tid < 192) {
    int q = tid - 128;
#pragma unroll
    for (int h = 0; h < 4; ++h) kl[q * 4 + h] = pj[q * 4 + h];
  }
  __syncthreads();
  float kn2 = 0.f;
#pragma unroll
  for (int w = 0; w < 64; ++w) kn2 += kwl[w] * kwl[w];
  float kn = sqrtf(kn2);
  if (tid < 64) knl[tid] = kwl[tid] / kn;
  for (int k = 2; k <= 128; k <<= 1) {
    for (int jj = k >> 1; jj > 0; jj >>= 1) {
      if (half == 0) {
        int ixj = n ^ jj;
        if (ixj > n) {
          float a1 = su[n], a2 = su[ixj];
          if (((n & k) == 0) ? (a1 > a2) : (a1 < a2)) { su[n] = a2; su[ixj] = a1; }
        }
      }
      __syncthreads();
    }
  }
  if (half == 0) lg[n] = logf(su[n]);
  __syncthreads();
  for (int off = 1; off < 128; off <<= 1) {
    float v = (half == 0 && n >= off) ? lg[n - off] : 0.f;
    __syncthreads();
    if (half == 0) lg[n] += v;
    __syncthreads();
  }
  float mrow[64];
  float score = -3.4e38f, e = 0.f, wwn = 0.f;
  if (half == 0) {
    float a_n = (1.f - su[n]) * expf(lg[n] - logf(su[n]));
    float sq = 0.f;
#pragma unroll
    for (int w = 0; w < 64; ++w) { float m = mem_s[n * 65 + w]; mrow[w] = m; sq += m * m; }
    float den = sqrtf(sq) + EPSF;
#pragma unroll
    for (int w = 0; w < 64; ++w) mrow[w] = mrow[w] / den;
    float dot = 0.f;
#pragma unroll
    for (int w = 0; w < 64; ++w) dot += mrow[w] * knl[w];
    score = dot * oneplus_(pj[340]);
    e = a_n;   // stash a_n
  }
  float mx = blk_max256(score, red, tid);
  float a_n = e;
  e = (half == 0) ? expf(score - mx) : 0.f;
  float esum = blk_sum256(e, red, tid);
  if (half == 0) {
    float cw = e / esum;
    float ag = sigm(pj[469]), wg = sigm(pj[470]);
    wwn = wg * (ag * a_n + (1.f - ag) * cw);
    wwp[n] = wwn; wwl[n] = wwn;
  }
  float sumww = blk_sum256((half == 0) ? wwn : 0.f, red, tid);
  if (half == 0) {
    float pn = (1.f - sumww) * pp[n] + wwn;
    pp[n] = pn; pl[n] = pn;
  }
  __syncthreads();
  if (half == 0) {
#pragma unroll
    for (int w = 0; w < 64; ++w) mem_s[n * 65 + w] = mrow[w] + wwn * dl[w];
  }
  {
    float wn = wwl[n], pcol = pl[n];
    int base = half * 64;
    for (int q = 0; q < 64; ++q) {
      int k2 = base + q;
      float v = lk_s[k2 * 129 + n] * (1.f - (wwl[k2] + wn)) + wwl[k2] * pcol;
      lk_s[k2 * 129 + n] = (k2 == n) ? 0.f : v;
    }
  }
  __syncthreads();

  if (half == 0) {
    float sq = 0.f;
#pragma unroll
    for (int w = 0; w < 64; ++w) { float m = mem_s[n * 65 + w]; mrow[w] = m; sq += m * m; }
    float den2 = sqrtf(sq) + EPSF;
#pragma unroll
    for (int w = 0; w < 64; ++w) { mrow[w] = mrow[w] / den2; mem_s[n * 65 + w] = mrow[w]; }
  }
  __syncthreads();
  float cr_[4];
#pragma unroll
  for (int h = 0; h < 4; ++h) {
    float s3 = 0.f;
#pragma unroll
    for (int w = 0; w < 64; ++w) { float kv = kl[w * 4 + h]; s3 += kv * kv; }
    float knh = sqrtf(s3);
    float sc = -3.4e38f;
    if (half == 0) {
      float d2 = 0.f;
#pragma unroll
      for (int w = 0; w < 64; ++w) d2 += mrow[w] * (kl[w * 4 + h] / knh);
      sc = d2 * oneplus_(pj[256 + h]);
    }
    float mxh = blk_max256(sc, red, tid);
    float eh = (half == 0) ? expf(sc - mxh) : 0.f;
    float ehs = blk_sum256(eh, red, tid);
    cr_[h] = eh / ehs;
  }
  {
    float f0 = 0, f1 = 0, f2 = 0, f3 = 0, b0 = 0, b1 = 0, b2 = 0, b3 = 0;
    int base = half * 64;
    for (int q = 0; q < 64; ++q) {
      int jj = base + q;
      float lrow = lk_s[n * 129 + jj];
      float lcol = lk_s[jj * 129 + n];
      float q0 = rwold[jj * 4], q1 = rwold[jj * 4 + 1], q2 = rwold[jj * 4 + 2], q3 = rwold[jj * 4 + 3];
      f0 += lrow * q0; f1 += lrow * q1; f2 += lrow * q2; f3 += lrow * q3;
      b0 += lcol * q0; b1 += lcol * q1; b2 += lcol * q2; b3 += lcol * q3;
    }
    int o = half * 512 + n * 4;
    fpart[o] = f0; fpart[o + 1] = f1; fpart[o + 2] = f2; fpart[o + 3] = f3;
    bpart[o] = b0; bpart[o + 1] = b1; bpart[o + 2] = b2; bpart[o + 3] = b3;
  }
  __syncthreads();
  if (half == 0) {
#pragma unroll
    for (int h = 0; h < 4; ++h) {
      float fv = fpart[n * 4 + h] + fpart[512 + n * 4 + h];
      float bv = bpart[n * 4 + h] + bpart[512 + n * 4 + h];
      float m0 = pj[264 + h], m1 = pj[264 + 4 + h], m2 = pj[264 + 8 + h];
      float mm = fmaxf(m0, fmaxf(m1, m2));
      float e0 = expf(m0 - mm), e1 = expf(m1 - mm), e2 = expf(m2 - mm);
      float inv = 1.f / (e0 + e1 + e2);
      float rwv = (e0 * inv) * bv + (e1 * inv) * cr_[h] + (e2 * inv) * fv;
      rwp[n * 4 + h] = rwv;
      rwnew[n * 4 + h] = rwv;
    }
  }
  __syncthreads();
  for (int i = tid; i < 8192; i += 256) memp[i] = mem_s[(i >> 6) * 65 + (i & 63)];
  for (int i = tid; i < 16384; i += 256) lk[i] = lk_s[(i >> 7) * 129 + (i & 127)];
  {
    int w2 = tid & 63, which = tid >> 6;
    float rv = 0.f;
    for (int jj = 0; jj < 128; ++jj) rv += mem_s[jj * 65 + w2] * rwnew[jj * 4 + which];
    ws[OFF_RV + (long)(t + 1) * 8192 + b * 256 + w2 * 4 + which] = rv;
  }
}

// ===== persistent Phase-A kernel: 128 blocks x 256 thr, cooperative ========
constexpr int SMEMF = 29120;   // floats (116,480 B)
__global__ void phaseA_kernel(PA p) {
  cg::grid_group grid = cg::this_grid();
  extern __shared__ float sm[];
  int blk = blockIdx.x;
  for (int t = 0; t < TN; ++t) {
    gates_body(p, t, sm);          // all 128 blocks
    grid.sync();
    if (blk < 120) proj_body(p, t, sm);
    grid.sync();
    if (blk < 32) memAB_body(p, t, sm);
    grid.sync();
  }
}

// ===== out_gemm (r12 exact): conflict-free micro-tile ======================
__global__ __launch_bounds__(256) void out_gemm(
    const float* __restrict__ ws, const float* __restrict__ Why_w,
    const float* __restrict__ Why_b, const float* __restrict__ Wry_w,
    float* __restrict__ out) {
  __shared__ float al[16 * 132];
  __shared__ float bl[16 * 132];
  const float* Hp  = ws + OFF_H + 32768;   // [2048][1024]
  const float* RVp = ws + OFF_RV + 8192;   // [2048][256]
  int tid = threadIdx.x;
  int tx = tid & 15, ty = tid >> 4;
  int col0 = blockIdx.x * 128, row0 = blockIdx.y * 128;
  float acc[8][8];
#pragma unroll
  for (int i = 0; i < 8; ++i)
#pragma unroll
    for (int j = 0; j < 8; ++j) acc[i][j] = 0.f;
  for (int kt = 0; kt < 80; ++kt) {
    int k0 = kt * 16;
    __syncthreads();
#pragma unroll
    for (int q = 0; q < 8; ++q) {
      int i2 = q * 256 + tid;
      int r = i2 >> 4, k = i2 & 15;
      int gk = k0 + k;
      float va = (gk < 1024) ? Hp[(long)(row0 + r) * 1024 + gk]
                             : RVp[(long)(row0 + r) * 256 + gk - 1024];
      al[k * 132 + r] = va;
      float vb = (gk < 1024) ? Why_w[(long)(col0 + r) * 1024 + gk]
                             : Wry_w[(long)(col0 + r) * 256 + gk - 1024];
      bl[k * 132 + r] = vb;
    }
    __syncthreads();
#pragma unroll
    for (int k = 0; k < 16; ++k) {
      float4 a0 = *(const float4*)&al[k * 132 + ty * 8];
      float4 a1 = *(const float4*)&al[k * 132 + ty * 8 + 4];
      float4 c0 = *(const float4*)&bl[k * 132 + tx * 4];
      float4 c1 = *(const float4*)&bl[k * 132 + 64 + tx * 4];
      float ar[8] = {a0.x, a0.y, a0.z, a0.w, a1.x, a1.y, a1.z, a1.w};
      float br[8] = {c0.x, c0.y, c0.z, c0.w, c1.x, c1.y, c1.z, c1.w};
#pragma unroll
      for (int i = 0; i < 8; ++i)
#pragma unroll
        for (int j = 0; j < 8; ++j) acc[i][j] += ar[i] * br[j];
    }
  }
  float4 bb0 = *(const float4*)&Why_b[col0 + tx * 4];
  float4 bb1 = *(const float4*)&Why_b[col0 + 64 + tx * 4];
  float bias[8] = {bb0.x, bb0.y, bb0.z, bb0.w, bb1.x, bb1.y, bb1.z, bb1.w};
#pragma unroll
  for (int i = 0; i < 8; ++i) {
    long r = row0 + ty * 8 + i;
    float* op0 = out + r * 16000 + col0 + tx * 4;
    float* op1 = out + r * 16000 + col0 + 64 + tx * 4;
    float4 o0 = {acc[i][0] + bias[0], acc[i][1] + bias[1], acc[i][2] + bias[2], acc[i][3] + bias[3]};
    float4 o1 = {acc[i][4] + bias[4], acc[i][5] + bias[5], acc[i][6] + bias[6], acc[i][7] + bias[7]};
    *(float4*)op0 = o0;
    *(float4*)op1 = o1;
  }
}

extern "C" void kernel_launch(void* const* d_in, const int* in_sizes, int n_in,
                              void* d_out, int out_size, void* d_ws, size_t ws_size,
                              hipStream_t stream) {
  const void* src_raw = d_in[0];
  const float* emb   = (const float*)d_in[1];
  const float* W_ih  = (const float*)d_in[2];
  const float* W_hh  = (const float*)d_in[3];
  const float* b_ih  = (const float*)d_in[4];
  const float* b_hh  = (const float*)d_in[5];
  const float* rk_w  = (const float*)d_in[6];
  const float* rk_b  = (const float*)d_in[7];
  const float* rs_w  = (const float*)d_in[8];
  const float* rs_b  = (const float*)d_in[9];
  const float* fg_w  = (const float*)d_in[10];
  const float* fg_b  = (const float*)d_in[11];
  const float* rm_w  = (const float*)d_in[12];
  const float* rm_b  = (const float*)d_in[13];
  const float* wk_w  = (const float*)d_in[14];
  const float* wk_b  = (const float*)d_in[15];
  const float* ws_w  = (const float*)d_in[16];
  const float* ws_b  = (const float*)d_in[17];
  const float* ev_w  = (const float*)d_in[18];
  const float* ev_b  = (const float*)d_in[19];
  const float* wv_w  = (const float*)d_in[20];
  const float* wv_b  = (const float*)d_in[21];
  const float* ag_w  = (const float*)d_in[22];
  const float* ag_b  = (const float*)d_in[23];
  const float* wg_w  = (const float*)d_in[24];
  const float* wg_b  = (const float*)d_in[25];
  const float* Why_w = (const float*)d_in[26];
  const float* Why_b = (const float*)d_in[27];
  const float* Wry_w = (const float*)d_in[28];
  float* ws = (float*)d_ws;
  float* out = (float*)d_out;

  src_decode<<<1, 256, 0, stream>>>(src_raw, ws);
  init_kernel<<<512, 256, 0, stream>>>(ws);

  PA pa;
  pa.emb = emb; pa.W_ih = W_ih; pa.W_hh = W_hh; pa.b_ih = b_ih; pa.b_hh = b_hh;
  pa.rk_w = rk_w; pa.rk_b = rk_b; pa.rs_w = rs_w; pa.rs_b = rs_b;
  pa.fg_w = fg_w; pa.fg_b = fg_b; pa.rm_w = rm_w; pa.rm_b = rm_b;
  pa.wk_w = wk_w; pa.wk_b = wk_b; pa.ws_w = ws_w; pa.ws_b = ws_b;
  pa.ev_w = ev_w; pa.ev_b = ev_b; pa.wv_w = wv_w; pa.wv_b = wv_b;
  pa.ag_w = ag_w; pa.ag_b = ag_b; pa.wg_w = wg_w; pa.wg_b = wg_b;
  pa.ws = ws;
  void* kargs[] = { (void*)&pa };
  hipLaunchCooperativeKernel((const void*)phaseA_kernel, dim3(128), dim3(256),
                             kargs, (unsigned)(SMEMF * sizeof(float)), stream);

  out_gemm<<<dim3(125, 16), 256, 0, stream>>>(ws, Why_w, Why_b, Wry_w, out);
}

// Round 14
// 12201.195 us; speedup vs baseline: 2.1872x; 2.1872x over previous
//
#include <hip/hip_runtime.h>
#include <math.h>

// ---- problem dims ----
#define TN 64
#define BN 32
#define EPSF 1e-6f

// ---- workspace layout (floats): full H/RV history for deferred out-GEMM ----
constexpr long OFF_H     = 0;                       // 65 * 32*1024
constexpr long OFF_RV    = OFF_H    + 65L*32768;    // 65 * 32*256
constexpr long OFF_S     = OFF_RV   + 65L*8192;     // 32768
constexpr long OFF_RW    = OFF_S    + 32768;        // B*N*HD = 16384
constexpr long OFF_WW    = OFF_RW   + 16384;        // B*N
constexpr long OFF_U     = OFF_WW   + 4096;
constexpr long OFF_P     = OFF_U    + 4096;
constexpr long OFF_MEM   = OFF_P    + 4096;         // B*N*WD = 262144
constexpr long OFF_LINKS = OFF_MEM  + 262144;       // B*N*N = 524288
constexpr long OFF_PROJ  = OFF_LINKS+ 524288;       // B*512 (471 used)
constexpr long OFF_SRC   = OFF_PROJ + 16384;        // 2048 ints
// total ≈ 14.1 MB (proven footprint)

__device__ __forceinline__ float sigm(float x) { return 1.f / (1.f + expf(-x)); }
__device__ __forceinline__ float oneplus_(float x) {
  return 1.f + fmaxf(x, 0.f) + log1pf(expf(-fabsf(x)));
}

// ===== src width auto-detect + decode to int32 (validated round 6) =========
__global__ void src_decode(const void* __restrict__ src_raw, float* __restrict__ ws) {
  __shared__ int is64_s;
  if (threadIdx.x == 0) is64_s = 1;
  __syncthreads();
  const long long* s64 = (const long long*)src_raw;
  for (int i = threadIdx.x; i < 1024; i += 256) {
    long long v = s64[i];
    if (v < 0 || v >= 32000) is64_s = 0;
  }
  __syncthreads();
  int* dst = (int*)(ws + OFF_SRC);
  if (is64_s) {
    for (int i = threadIdx.x; i < 2048; i += 256) dst[i] = (int)s64[i];
  } else {
    const int* s32 = (const int*)src_raw;
    for (int i = threadIdx.x; i < 2048; i += 256) dst[i] = s32[i];
  }
}

// ================= init: H slot0, RV slot0, state; U=EPS ====================
__global__ void init_kernel(float* ws) {
  long i0 = (long)blockIdx.x * blockDim.x + threadIdx.x;
  long stride = (long)gridDim.x * blockDim.x;
  for (long x = i0; x < 32768; x += stride) ws[OFF_H + x] = 0.f;
  for (long x = i0; x < 8192;  x += stride) ws[OFF_RV + x] = 0.f;
  const long zlen = OFF_PROJ - OFF_S;
  for (long x = i0; x < zlen; x += stride) {
    long g = OFF_S + x;
    ws[g] = (g >= OFF_U && g < OFF_U + 4096) ? EPSF : 0.f;
  }
}

// ===== gates_v3: 512 blocks x 256 thr; 2 j/block, 4-way k-split per (b,j) ==
// wave = tid>>6; jg = wave>>1; qpair = wave&1; b = lane&31; qsub = lane>>5.
// Thread sums k-quarter q = qpair*2+qsub of all 4 gates for (b, j=blk*2+jg).
__global__ __launch_bounds__(256) void gates_kernel(
    int t, const float* __restrict__ emb,
    const float* __restrict__ W_ih, const float* __restrict__ W_hh,
    const float* __restrict__ b_ih, const float* __restrict__ b_hh,
    float* __restrict__ ws) {
  __shared__ float xl[32 * 260];
  __shared__ float rb[512];
  int tid = threadIdx.x;
  int wave = tid >> 6, lane = tid & 63;
  int jg = wave >> 1, qpair = wave & 1;
  int b = lane & 31, qsub = lane >> 5;
  int q = qpair * 2 + qsub;
  int j = blockIdx.x * 2 + jg;
  const int* src = (const int*)(ws + OFF_SRC);
  float acc0 = 0.f, acc1 = 0.f, acc2 = 0.f, acc3 = 0.f;
  for (int c = 0; c < 7; ++c) {
    __syncthreads();
#pragma unroll
    for (int qq = 0; qq < 32; ++qq) {
      int i2 = qq * 256 + tid;
      int bb = i2 >> 8, kk = i2 & 255;
      float v;
      if (c < 2)       v = emb[(long)src[t * 32 + bb] * 512 + c * 256 + kk];
      else if (c == 2) v = ws[OFF_RV + (long)t * 8192 + bb * 256 + kk];
      else             v = ws[OFF_H + (long)t * 32768 + bb * 1024 + (c - 3) * 256 + kk];
      xl[bb * 260 + kk] = v;
    }
    __syncthreads();
    const float* xp = &xl[b * 260 + q * 64];
    const float *w0, *w1, *w2, *w3;
    if (c < 3) {
      long base = c * 256 + q * 64;
      w0 = W_ih + (long)j * 768 + base;
      w1 = W_ih + (long)(1024 + j) * 768 + base;
      w2 = W_ih + (long)(2048 + j) * 768 + base;
      w3 = W_ih + (long)(3072 + j) * 768 + base;
    } else {
      long base = (c - 3) * 256 + q * 64;
      w0 = W_hh + (long)j * 1024 + base;
      w1 = W_hh + (long)(1024 + j) * 1024 + base;
      w2 = W_hh + (long)(2048 + j) * 1024 + base;
      w3 = W_hh + (long)(3072 + j) * 1024 + base;
    }
#pragma unroll
    for (int k = 0; k < 64; k += 4) {
      float4 xv = *(const float4*)(xp + k);
      float4 a = *(const float4*)(w0 + k);
      float4 bb4 = *(const float4*)(w1 + k);
      float4 cc4 = *(const float4*)(w2 + k);
      float4 dd4 = *(const float4*)(w3 + k);
      acc0 += xv.x * a.x + xv.y * a.y + xv.z * a.z + xv.w * a.w;
      acc1 += xv.x * bb4.x + xv.y * bb4.y + xv.z * bb4.z + xv.w * bb4.w;
      acc2 += xv.x * cc4.x + xv.y * cc4.y + xv.z * cc4.z + xv.w * cc4.w;
      acc3 += xv.x * dd4.x + xv.y * dd4.y + xv.z * dd4.z + xv.w * dd4.w;
    }
  }
  // combine qsub halves within wave (both lanes end with the pair-sum)
  acc0 += __shfl_xor(acc0, 32);
  acc1 += __shfl_xor(acc1, 32);
  acc2 += __shfl_xor(acc2, 32);
  acc3 += __shfl_xor(acc3, 32);
  if (qsub == 0) {
    rb[0 * 128 + jg * 64 + qpair * 32 + b] = acc0;
    rb[1 * 128 + jg * 64 + qpair * 32 + b] = acc1;
    rb[2 * 128 + jg * 64 + qpair * 32 + b] = acc2;
    rb[3 * 128 + jg * 64 + qpair * 32 + b] = acc3;
  }
  __syncthreads();
  if (tid < 64) {
    int jge = tid >> 5, be = tid & 31;
    int jj = blockIdx.x * 2 + jge;
    float gi = rb[0 * 128 + jge * 64 + be] + rb[0 * 128 + jge * 64 + 32 + be] + b_ih[jj] + b_hh[jj];
    float gf = rb[1 * 128 + jge * 64 + be] + rb[1 * 128 + jge * 64 + 32 + be] + b_ih[1024 + jj] + b_hh[1024 + jj];
    float gg = rb[2 * 128 + jge * 64 + be] + rb[2 * 128 + jge * 64 + 32 + be] + b_ih[2048 + jj] + b_hh[2048 + jj];
    float go = rb[3 * 128 + jge * 64 + be] + rb[3 * 128 + jge * 64 + 32 + be] + b_ih[3072 + jj] + b_hh[3072 + jj];
    long si = (long)be * 1024 + jj;
    float sv = sigm(gf) * ws[OFF_S + si] + sigm(gi) * tanhf(gg);
    ws[OFF_S + si] = sv;
    ws[OFF_H + (long)(t + 1) * 32768 + si] = sigm(go) * tanhf(sv);
  }
}

// ===== proj_v2: 240 blocks (8 outputs x 8 batches); h in LDS; w in regs ====
__global__ __launch_bounds__(256) void proj_kernel(
    int t, float* __restrict__ ws,
    const float* rk_w, const float* rk_b, const float* rs_w, const float* rs_b,
    const float* fg_w, const float* fg_b, const float* rm_w, const float* rm_b,
    const float* wk_w, const float* wk_b, const float* ws_w, const float* ws_b,
    const float* ev_w, const float* ev_b, const float* wv_w, const float* wv_b,
    const float* ag_w, const float* ag_b, const float* wg_w, const float* wg_b) {
  __shared__ float h_s[8][1032];
  int obase = blockIdx.x * 8;
  int bbase = blockIdx.y * 8;
  int tid = threadIdx.x;
  for (int q = 0; q < 32; ++q) {
    int idx = q * 256 + tid;          // 0..8191
    int bb = idx >> 10, kk = idx & 1023;
    h_s[bb][kk] = ws[OFF_H + (long)(t + 1) * 32768 + (long)(bbase + bb) * 1024 + kk];
  }
  __syncthreads();
  int wv = tid >> 6, lane = tid & 63;
  for (int oi = wv; oi < 8; oi += 4) {
    int o = obase + oi;
    if (o >= 471) continue;   // wave-uniform
    const float* w;
    float bias;
    if (o < 256)      { int wi = o >> 2, hh = o & 3; w = rk_w + (long)(hh * 64 + wi) * 1024; bias = rk_b[hh * 64 + wi]; }
    else if (o < 260) { int q2 = o - 256; w = rs_w + (long)q2 * 1024; bias = rs_b[q2]; }
    else if (o < 264) { int q2 = o - 260; w = fg_w + (long)q2 * 1024; bias = fg_b[q2]; }
    else if (o < 276) { int q2 = o - 264, m = q2 >> 2, hh = q2 & 3; w = rm_w + (long)(hh * 3 + m) * 1024; bias = rm_b[hh * 3 + m]; }
    else if (o < 340) { int q2 = o - 276; w = wk_w + (long)q2 * 1024; bias = wk_b[q2]; }
    else if (o == 340){ w = ws_w; bias = ws_b[0]; }
    else if (o < 405) { int q2 = o - 341; w = ev_w + (long)q2 * 1024; bias = ev_b[q2]; }
    else if (o < 469) { int q2 = o - 405; w = wv_w + (long)q2 * 1024; bias = wv_b[q2]; }
    else if (o == 469){ w = ag_w; bias = ag_b[0]; }
    else              { w = wg_w; bias = wg_b[0]; }
    float wreg[16];
#pragma unroll
    for (int i = 0; i < 16; ++i) wreg[i] = w[lane + 64 * i];
#pragma unroll
    for (int bb = 0; bb < 8; ++bb) {
      float s = 0.f;
#pragma unroll
      for (int i = 0; i < 16; ++i) s += h_s[bb][lane + 64 * i] * wreg[i];
#pragma unroll
      for (int off = 32; off; off >>= 1) s += __shfl_xor(s, off);
      if (lane == 0) ws[OFF_PROJ + (long)(bbase + bb) * 512 + o] = s + bias;
    }
  }
}

// ===== reductions over 256 threads =====
__device__ __forceinline__ float blk_max256(float v, float* red, int tid) {
  red[tid] = v; __syncthreads();
#pragma unroll
  for (int s = 128; s > 0; s >>= 1) { if (tid < s) red[tid] = fmaxf(red[tid], red[tid + s]); __syncthreads(); }
  float r = red[0]; __syncthreads();
  return r;
}
__device__ __forceinline__ float blk_sum256(float v, float* red, int tid) {
  red[tid] = v; __syncthreads();
#pragma unroll
  for (int s = 128; s > 0; s >>= 1) { if (tid < s) red[tid] += red[tid + s]; __syncthreads(); }
  float r = red[0]; __syncthreads();
  return r;
}

// ===== memAB (r12 exact): mem AND links in LDS; 32 blk x 256 thr ===========
constexpr int SMEMF = 8320 + 16512 + 256 + 4*128 + 3*64 + 256 + 512 + 512 + 1024 + 1024;
__global__ __launch_bounds__(256) void memAB_kernel(int t, float* __restrict__ ws) {
  extern __shared__ float sm[];
  float* mem_s = sm;               // [128][65]
  float* lk_s  = sm + 8320;        // [128][129]
  float* red   = sm + 24832;       // 256
  float* su    = sm + 25088;       // 128
  float* lg    = sm + 25216;       // 128
  float* wwl   = sm + 25344;       // 128
  float* pl    = sm + 25472;       // 128
  float* kwl   = sm + 25600;       // 64
  float* knl   = sm + 25664;       // 64
  float* dl    = sm + 25728;       // 64
  float* kl    = sm + 25792;       // 256
  float* rwold = sm + 26048;       // 512
  float* rwnew = sm + 26560;       // 512
  float* fpart = sm + 27072;       // 1024
  float* bpart = sm + 28096;       // 1024
  int b = blockIdx.x, tid = threadIdx.x;
  int n = tid & 127, half = tid >> 7;
  const float* pj = ws + OFF_PROJ + b * 512;
  float* u    = ws + OFF_U  + b * 128;
  float* wwp  = ws + OFF_WW + b * 128;
  float* pp   = ws + OFF_P  + b * 128;
  float* rwp  = ws + OFF_RW + b * 512;
  float* memp = ws + OFF_MEM + (long)b * 8192;
  float* lk   = ws + OFF_LINKS + (long)b * 16384;

  for (int i = tid; i < 8192; i += 256) mem_s[(i >> 6) * 65 + (i & 63)] = memp[i];
  for (int i = tid; i < 16384; i += 256) lk_s[(i >> 7) * 129 + (i & 127)] = lk[i];

  if (half == 0) {
    float fg0 = sigm(pj[260]), fg1 = sigm(pj[261]), fg2 = sigm(pj[262]), fg3 = sigm(pj[263]);
    float r0 = rwp[n * 4], r1 = rwp[n * 4 + 1], r2 = rwp[n * 4 + 2], r3 = rwp[n * 4 + 3];
    rwold[n * 4] = r0; rwold[n * 4 + 1] = r1; rwold[n * 4 + 2] = r2; rwold[n * 4 + 3] = r3;
    float psi = expf(logf(1.f - fg0 * r0) + logf(1.f - fg1 * r1) +
                     logf(1.f - fg2 * r2) + logf(1.f - fg3 * r3));
    float uu = u[n], wwo = wwp[n];
    uu = (uu + wwo - uu * wwo) * psi;
    u[n] = uu;
    su[n] = uu;
  }
  if (tid < 64) {
    kwl[tid] = pj[276 + tid];
    dl[tid] = sigm(pj[405 + tid]) - sigm(pj[341 + tid]);  // writev - erase
  }
  if (tid >= 128 && tid < 192) {
    int q = tid - 128;
#pragma unroll
    for (int h = 0; h < 4; ++h) kl[q * 4 + h] = pj[q * 4 + h];
  }
  __syncthreads();
  float kn2 = 0.f;
#pragma unroll
  for (int w = 0; w < 64; ++w) kn2 += kwl[w] * kwl[w];
  float kn = sqrtf(kn2);
  if (tid < 64) knl[tid] = kwl[tid] / kn;
  for (int k = 2; k <= 128; k <<= 1) {
    for (int jj = k >> 1; jj > 0; jj >>= 1) {
      if (half == 0) {
        int ixj = n ^ jj;
        if (ixj > n) {
          float a1 = su[n], a2 = su[ixj];
          if (((n & k) == 0) ? (a1 > a2) : (a1 < a2)) { su[n] = a2; su[ixj] = a1; }
        }
      }
      __syncthreads();
    }
  }
  if (half == 0) lg[n] = logf(su[n]);
  __syncthreads();
  for (int off = 1; off < 128; off <<= 1) {
    float v = (half == 0 && n >= off) ? lg[n - off] : 0.f;
    __syncthreads();
    if (half == 0) lg[n] += v;
    __syncthreads();
  }
  float mrow[64];
  float score = -3.4e38f, e = 0.f, wwn = 0.f;
  if (half == 0) {
    float a_n = (1.f - su[n]) * expf(lg[n] - logf(su[n]));
    float sq = 0.f;
#pragma unroll
    for (int w = 0; w < 64; ++w) { float m = mem_s[n * 65 + w]; mrow[w] = m; sq += m * m; }
    float den = sqrtf(sq) + EPSF;
#pragma unroll
    for (int w = 0; w < 64; ++w) mrow[w] = mrow[w] / den;
    float dot = 0.f;
#pragma unroll
    for (int w = 0; w < 64; ++w) dot += mrow[w] * knl[w];
    score = dot * oneplus_(pj[340]);
    e = a_n;   // stash a_n
  }
  float mx = blk_max256(score, red, tid);
  float a_n = e;
  e = (half == 0) ? expf(score - mx) : 0.f;
  float esum = blk_sum256(e, red, tid);
  if (half == 0) {
    float cw = e / esum;
    float ag = sigm(pj[469]), wg = sigm(pj[470]);
    wwn = wg * (ag * a_n + (1.f - ag) * cw);
    wwp[n] = wwn; wwl[n] = wwn;
  }
  float sumww = blk_sum256((half == 0) ? wwn : 0.f, red, tid);
  if (half == 0) {
    float pn = (1.f - sumww) * pp[n] + wwn;
    pp[n] = pn; pl[n] = pn;
  }
  __syncthreads();
  if (half == 0) {
#pragma unroll
    for (int w = 0; w < 64; ++w) mem_s[n * 65 + w] = mrow[w] + wwn * dl[w];
  }
  {
    float wn = wwl[n], pcol = pl[n];
    int base = half * 64;
    for (int q = 0; q < 64; ++q) {
      int k2 = base + q;
      float v = lk_s[k2 * 129 + n] * (1.f - (wwl[k2] + wn)) + wwl[k2] * pcol;
      lk_s[k2 * 129 + n] = (k2 == n) ? 0.f : v;
    }
  }
  __syncthreads();

  if (half == 0) {
    float sq = 0.f;
#pragma unroll
    for (int w = 0; w < 64; ++w) { float m = mem_s[n * 65 + w]; mrow[w] = m; sq += m * m; }
    float den2 = sqrtf(sq) + EPSF;
#pragma unroll
    for (int w = 0; w < 64; ++w) { mrow[w] = mrow[w] / den2; mem_s[n * 65 + w] = mrow[w]; }
  }
  __syncthreads();
  float cr_[4];
#pragma unroll
  for (int h = 0; h < 4; ++h) {
    float s3 = 0.f;
#pragma unroll
    for (int w = 0; w < 64; ++w) { float kv = kl[w * 4 + h]; s3 += kv * kv; }
    float knh = sqrtf(s3);
    float sc = -3.4e38f;
    if (half == 0) {
      float d2 = 0.f;
#pragma unroll
      for (int w = 0; w < 64; ++w) d2 += mrow[w] * (kl[w * 4 + h] / knh);
      sc = d2 * oneplus_(pj[256 + h]);
    }
    float mxh = blk_max256(sc, red, tid);
    float eh = (half == 0) ? expf(sc - mxh) : 0.f;
    float ehs = blk_sum256(eh, red, tid);
    cr_[h] = eh / ehs;
  }
  {
    float f0 = 0, f1 = 0, f2 = 0, f3 = 0, b0 = 0, b1 = 0, b2 = 0, b3 = 0;
    int base = half * 64;
    for (int q = 0; q < 64; ++q) {
      int jj = base + q;
      float lrow = lk_s[n * 129 + jj];
      float lcol = lk_s[jj * 129 + n];
      float q0 = rwold[jj * 4], q1 = rwold[jj * 4 + 1], q2 = rwold[jj * 4 + 2], q3 = rwold[jj * 4 + 3];
      f0 += lrow * q0; f1 += lrow * q1; f2 += lrow * q2; f3 += lrow * q3;
      b0 += lcol * q0; b1 += lcol * q1; b2 += lcol * q2; b3 += lcol * q3;
    }
    int o = half * 512 + n * 4;
    fpart[o] = f0; fpart[o + 1] = f1; fpart[o + 2] = f2; fpart[o + 3] = f3;
    bpart[o] = b0; bpart[o + 1] = b1; bpart[o + 2] = b2; bpart[o + 3] = b3;
  }
  __syncthreads();
  if (half == 0) {
#pragma unroll
    for (int h = 0; h < 4; ++h) {
      float fv = fpart[n * 4 + h] + fpart[512 + n * 4 + h];
      float bv = bpart[n * 4 + h] + bpart[512 + n * 4 + h];
      float m0 = pj[264 + h], m1 = pj[264 + 4 + h], m2 = pj[264 + 8 + h];
      float mm = fmaxf(m0, fmaxf(m1, m2));
      float e0 = expf(m0 - mm), e1 = expf(m1 - mm), e2 = expf(m2 - mm);
      float inv = 1.f / (e0 + e1 + e2);
      float rwv = (e0 * inv) * bv + (e1 * inv) * cr_[h] + (e2 * inv) * fv;
      rwp[n * 4 + h] = rwv;
      rwnew[n * 4 + h] = rwv;
    }
  }
  __syncthreads();
  for (int i = tid; i < 8192; i += 256) memp[i] = mem_s[(i >> 6) * 65 + (i & 63)];
  for (int i = tid; i < 16384; i += 256) lk[i] = lk_s[(i >> 7) * 129 + (i & 127)];
  {
    int w2 = tid & 63, which = tid >> 6;
    float rv = 0.f;
    for (int jj = 0; jj < 128; ++jj) rv += mem_s[jj * 65 + w2] * rwnew[jj * 4 + which];
    ws[OFF_RV + (long)(t + 1) * 8192 + b * 256 + w2 * 4 + which] = rv;
  }
}

// ===== out_gemm (r12 exact): conflict-free micro-tile ======================
__global__ __launch_bounds__(256) void out_gemm(
    const float* __restrict__ ws, const float* __restrict__ Why_w,
    const float* __restrict__ Why_b, const float* __restrict__ Wry_w,
    float* __restrict__ out) {
  __shared__ float al[16 * 132];
  __shared__ float bl[16 * 132];
  const float* Hp  = ws + OFF_H + 32768;   // [2048][1024]
  const float* RVp = ws + OFF_RV + 8192;   // [2048][256]
  int tid = threadIdx.x;
  int tx = tid & 15, ty = tid >> 4;
  int col0 = blockIdx.x * 128, row0 = blockIdx.y * 128;
  float acc[8][8];
#pragma unroll
  for (int i = 0; i < 8; ++i)
#pragma unroll
    for (int j = 0; j < 8; ++j) acc[i][j] = 0.f;
  for (int kt = 0; kt < 80; ++kt) {
    int k0 = kt * 16;
    __syncthreads();
#pragma unroll
    for (int q = 0; q < 8; ++q) {
      int i2 = q * 256 + tid;
      int r = i2 >> 4, k = i2 & 15;
      int gk = k0 + k;
      float va = (gk < 1024) ? Hp[(long)(row0 + r) * 1024 + gk]
                             : RVp[(long)(row0 + r) * 256 + gk - 1024];
      al[k * 132 + r] = va;
      float vb = (gk < 1024) ? Why_w[(long)(col0 + r) * 1024 + gk]
                             : Wry_w[(long)(col0 + r) * 256 + gk - 1024];
      bl[k * 132 + r] = vb;
    }
    __syncthreads();
#pragma unroll
    for (int k = 0; k < 16; ++k) {
      float4 a0 = *(const float4*)&al[k * 132 + ty * 8];
      float4 a1 = *(const float4*)&al[k * 132 + ty * 8 + 4];
      float4 c0 = *(const float4*)&bl[k * 132 + tx * 4];
      float4 c1 = *(const float4*)&bl[k * 132 + 64 + tx * 4];
      float ar[8] = {a0.x, a0.y, a0.z, a0.w, a1.x, a1.y, a1.z, a1.w};
      float br[8] = {c0.x, c0.y, c0.z, c0.w, c1.x, c1.y, c1.z, c1.w};
#pragma unroll
      for (int i = 0; i < 8; ++i)
#pragma unroll
        for (int j = 0; j < 8; ++j) acc[i][j] += ar[i] * br[j];
    }
  }
  float4 bb0 = *(const float4*)&Why_b[col0 + tx * 4];
  float4 bb1 = *(const float4*)&Why_b[col0 + 64 + tx * 4];
  float bias[8] = {bb0.x, bb0.y, bb0.z, bb0.w, bb1.x, bb1.y, bb1.z, bb1.w};
#pragma unroll
  for (int i = 0; i < 8; ++i) {
    long r = row0 + ty * 8 + i;
    float* op0 = out + r * 16000 + col0 + tx * 4;
    float* op1 = out + r * 16000 + col0 + 64 + tx * 4;
    float4 o0 = {acc[i][0] + bias[0], acc[i][1] + bias[1], acc[i][2] + bias[2], acc[i][3] + bias[3]};
    float4 o1 = {acc[i][4] + bias[4], acc[i][5] + bias[5], acc[i][6] + bias[6], acc[i][7] + bias[7]};
    *(float4*)op0 = o0;
    *(float4*)op1 = o1;
  }
}

extern "C" void kernel_launch(void* const* d_in, const int* in_sizes, int n_in,
                              void* d_out, int out_size, void* d_ws, size_t ws_size,
                              hipStream_t stream) {
  const void* src_raw = d_in[0];
  const float* emb   = (const float*)d_in[1];
  const float* W_ih  = (const float*)d_in[2];
  const float* W_hh  = (const float*)d_in[3];
  const float* b_ih  = (const float*)d_in[4];
  const float* b_hh  = (const float*)d_in[5];
  const float* rk_w  = (const float*)d_in[6];
  const float* rk_b  = (const float*)d_in[7];
  const float* rs_w  = (const float*)d_in[8];
  const float* rs_b  = (const float*)d_in[9];
  const float* fg_w  = (const float*)d_in[10];
  const float* fg_b  = (const float*)d_in[11];
  const float* rm_w  = (const float*)d_in[12];
  const float* rm_b  = (const float*)d_in[13];
  const float* wk_w  = (const float*)d_in[14];
  const float* wk_b  = (const float*)d_in[15];
  const float* ws_w  = (const float*)d_in[16];
  const float* ws_b  = (const float*)d_in[17];
  const float* ev_w  = (const float*)d_in[18];
  const float* ev_b  = (const float*)d_in[19];
  const float* wv_w  = (const float*)d_in[20];
  const float* wv_b  = (const float*)d_in[21];
  const float* ag_w  = (const float*)d_in[22];
  const float* ag_b  = (const float*)d_in[23];
  const float* wg_w  = (const float*)d_in[24];
  const float* wg_b  = (const float*)d_in[25];
  const float* Why_w = (const float*)d_in[26];
  const float* Why_b = (const float*)d_in[27];
  const float* Wry_w = (const float*)d_in[28];
  float* ws = (float*)d_ws;
  float* out = (float*)d_out;

  src_decode<<<1, 256, 0, stream>>>(src_raw, ws);
  init_kernel<<<512, 256, 0, stream>>>(ws);
  const size_t smem_bytes = (size_t)SMEMF * sizeof(float);  // ~116 KB
  for (int t = 0; t < TN; ++t) {
    gates_kernel<<<512, 256, 0, stream>>>(t, emb, W_ih, W_hh, b_ih, b_hh, ws);
    proj_kernel<<<dim3(60, 4), 256, 0, stream>>>(t, ws, rk_w, rk_b, rs_w, rs_b, fg_w, fg_b,
                                                 rm_w, rm_b, wk_w, wk_b, ws_w, ws_b,
                                                 ev_w, ev_b, wv_w, wv_b, ag_w, ag_b, wg_w, wg_b);
    memAB_kernel<<<32, 256, smem_bytes, stream>>>(t, ws);
  }
  out_gemm<<<dim3(125, 16), 256, 0, stream>>>(ws, Why_w, Why_b, Wry_w, out);
}

// Round 15
// 11768.391 us; speedup vs baseline: 2.2676x; 1.0368x over previous
//
#include <hip/hip_runtime.h>
#include <math.h>

// ---- problem dims ----
#define TN 64
#define BN 32
#define EPSF 1e-6f

// ---- workspace layout (floats): full H/RV history for deferred out-GEMM ----
constexpr long OFF_H     = 0;                       // 65 * 32*1024
constexpr long OFF_RV    = OFF_H    + 65L*32768;    // 65 * 32*256
constexpr long OFF_S     = OFF_RV   + 65L*8192;     // 32768
constexpr long OFF_RW    = OFF_S    + 32768;        // B*N*HD = 16384
constexpr long OFF_WW    = OFF_RW   + 16384;        // B*N
constexpr long OFF_U     = OFF_WW   + 4096;
constexpr long OFF_P     = OFF_U    + 4096;
constexpr long OFF_MEM   = OFF_P    + 4096;         // B*N*WD = 262144
constexpr long OFF_LINKS = OFF_MEM  + 262144;       // B*N*N = 524288
constexpr long OFF_PROJ  = OFF_LINKS+ 524288;       // B*512 (471 used)
constexpr long OFF_SRC   = OFF_PROJ + 16384;        // 2048 ints
// total ≈ 14.1 MB (proven footprint)

__device__ __forceinline__ float sigm(float x) { return 1.f / (1.f + expf(-x)); }
__device__ __forceinline__ float oneplus_(float x) {
  return 1.f + fmaxf(x, 0.f) + log1pf(expf(-fabsf(x)));
}

// ===== src width auto-detect + decode to int32 (validated round 6) =========
__global__ void src_decode(const void* __restrict__ src_raw, float* __restrict__ ws) {
  __shared__ int is64_s;
  if (threadIdx.x == 0) is64_s = 1;
  __syncthreads();
  const long long* s64 = (const long long*)src_raw;
  for (int i = threadIdx.x; i < 1024; i += 256) {
    long long v = s64[i];
    if (v < 0 || v >= 32000) is64_s = 0;
  }
  __syncthreads();
  int* dst = (int*)(ws + OFF_SRC);
  if (is64_s) {
    for (int i = threadIdx.x; i < 2048; i += 256) dst[i] = (int)s64[i];
  } else {
    const int* s32 = (const int*)src_raw;
    for (int i = threadIdx.x; i < 2048; i += 256) dst[i] = s32[i];
  }
}

// ================= init: H slot0, RV slot0, state; U=EPS ====================
__global__ void init_kernel(float* ws) {
  long i0 = (long)blockIdx.x * blockDim.x + threadIdx.x;
  long stride = (long)gridDim.x * blockDim.x;
  for (long x = i0; x < 32768; x += stride) ws[OFF_H + x] = 0.f;
  for (long x = i0; x < 8192;  x += stride) ws[OFF_RV + x] = 0.f;
  const long zlen = OFF_PROJ - OFF_S;
  for (long x = i0; x < zlen; x += stride) {
    long g = OFF_S + x;
    ws[g] = (g >= OFF_U && g < OFF_U + 4096) ? EPSF : 0.f;
  }
}

// ===== gates (r14 exact): 512 blocks x 256 thr; 2 j/block, 4-way k-split ===
__global__ __launch_bounds__(256) void gates_kernel(
    int t, const float* __restrict__ emb,
    const float* __restrict__ W_ih, const float* __restrict__ W_hh,
    const float* __restrict__ b_ih, const float* __restrict__ b_hh,
    float* __restrict__ ws) {
  __shared__ float xl[32 * 260];
  __shared__ float rb[512];
  int tid = threadIdx.x;
  int wave = tid >> 6, lane = tid & 63;
  int jg = wave >> 1, qpair = wave & 1;
  int b = lane & 31, qsub = lane >> 5;
  int q = qpair * 2 + qsub;
  int j = blockIdx.x * 2 + jg;
  const int* src = (const int*)(ws + OFF_SRC);
  float acc0 = 0.f, acc1 = 0.f, acc2 = 0.f, acc3 = 0.f;
  for (int c = 0; c < 7; ++c) {
    __syncthreads();
#pragma unroll
    for (int qq = 0; qq < 32; ++qq) {
      int i2 = qq * 256 + tid;
      int bb = i2 >> 8, kk = i2 & 255;
      float v;
      if (c < 2)       v = emb[(long)src[t * 32 + bb] * 512 + c * 256 + kk];
      else if (c == 2) v = ws[OFF_RV + (long)t * 8192 + bb * 256 + kk];
      else             v = ws[OFF_H + (long)t * 32768 + bb * 1024 + (c - 3) * 256 + kk];
      xl[bb * 260 + kk] = v;
    }
    __syncthreads();
    const float* xp = &xl[b * 260 + q * 64];
    const float *w0, *w1, *w2, *w3;
    if (c < 3) {
      long base = c * 256 + q * 64;
      w0 = W_ih + (long)j * 768 + base;
      w1 = W_ih + (long)(1024 + j) * 768 + base;
      w2 = W_ih + (long)(2048 + j) * 768 + base;
      w3 = W_ih + (long)(3072 + j) * 768 + base;
    } else {
      long base = (c - 3) * 256 + q * 64;
      w0 = W_hh + (long)j * 1024 + base;
      w1 = W_hh + (long)(1024 + j) * 1024 + base;
      w2 = W_hh + (long)(2048 + j) * 1024 + base;
      w3 = W_hh + (long)(3072 + j) * 1024 + base;
    }
#pragma unroll
    for (int k = 0; k < 64; k += 4) {
      float4 xv = *(const float4*)(xp + k);
      float4 a = *(const float4*)(w0 + k);
      float4 bb4 = *(const float4*)(w1 + k);
      float4 cc4 = *(const float4*)(w2 + k);
      float4 dd4 = *(const float4*)(w3 + k);
      acc0 += xv.x * a.x + xv.y * a.y + xv.z * a.z + xv.w * a.w;
      acc1 += xv.x * bb4.x + xv.y * bb4.y + xv.z * bb4.z + xv.w * bb4.w;
      acc2 += xv.x * cc4.x + xv.y * cc4.y + xv.z * cc4.z + xv.w * cc4.w;
      acc3 += xv.x * dd4.x + xv.y * dd4.y + xv.z * dd4.z + xv.w * dd4.w;
    }
  }
  acc0 += __shfl_xor(acc0, 32);
  acc1 += __shfl_xor(acc1, 32);
  acc2 += __shfl_xor(acc2, 32);
  acc3 += __shfl_xor(acc3, 32);
  if (qsub == 0) {
    rb[0 * 128 + jg * 64 + qpair * 32 + b] = acc0;
    rb[1 * 128 + jg * 64 + qpair * 32 + b] = acc1;
    rb[2 * 128 + jg * 64 + qpair * 32 + b] = acc2;
    rb[3 * 128 + jg * 64 + qpair * 32 + b] = acc3;
  }
  __syncthreads();
  if (tid < 64) {
    int jge = tid >> 5, be = tid & 31;
    int jj = blockIdx.x * 2 + jge;
    float gi = rb[0 * 128 + jge * 64 + be] + rb[0 * 128 + jge * 64 + 32 + be] + b_ih[jj] + b_hh[jj];
    float gf = rb[1 * 128 + jge * 64 + be] + rb[1 * 128 + jge * 64 + 32 + be] + b_ih[1024 + jj] + b_hh[1024 + jj];
    float gg = rb[2 * 128 + jge * 64 + be] + rb[2 * 128 + jge * 64 + 32 + be] + b_ih[2048 + jj] + b_hh[2048 + jj];
    float go = rb[3 * 128 + jge * 64 + be] + rb[3 * 128 + jge * 64 + 32 + be] + b_ih[3072 + jj] + b_hh[3072 + jj];
    long si = (long)be * 1024 + jj;
    float sv = sigm(gf) * ws[OFF_S + si] + sigm(gi) * tanhf(gg);
    ws[OFF_S + si] = sv;
    ws[OFF_H + (long)(t + 1) * 32768 + si] = sigm(go) * tanhf(sv);
  }
}

// ===== proj (r14 exact): 240 blocks (8 outputs x 8 batches) ================
__global__ __launch_bounds__(256) void proj_kernel(
    int t, float* __restrict__ ws,
    const float* rk_w, const float* rk_b, const float* rs_w, const float* rs_b,
    const float* fg_w, const float* fg_b, const float* rm_w, const float* rm_b,
    const float* wk_w, const float* wk_b, const float* ws_w, const float* ws_b,
    const float* ev_w, const float* ev_b, const float* wv_w, const float* wv_b,
    const float* ag_w, const float* ag_b, const float* wg_w, const float* wg_b) {
  __shared__ float h_s[8][1032];
  int obase = blockIdx.x * 8;
  int bbase = blockIdx.y * 8;
  int tid = threadIdx.x;
  for (int q = 0; q < 32; ++q) {
    int idx = q * 256 + tid;          // 0..8191
    int bb = idx >> 10, kk = idx & 1023;
    h_s[bb][kk] = ws[OFF_H + (long)(t + 1) * 32768 + (long)(bbase + bb) * 1024 + kk];
  }
  __syncthreads();
  int wv = tid >> 6, lane = tid & 63;
  for (int oi = wv; oi < 8; oi += 4) {
    int o = obase + oi;
    if (o >= 471) continue;   // wave-uniform
    const float* w;
    float bias;
    if (o < 256)      { int wi = o >> 2, hh = o & 3; w = rk_w + (long)(hh * 64 + wi) * 1024; bias = rk_b[hh * 64 + wi]; }
    else if (o < 260) { int q2 = o - 256; w = rs_w + (long)q2 * 1024; bias = rs_b[q2]; }
    else if (o < 264) { int q2 = o - 260; w = fg_w + (long)q2 * 1024; bias = fg_b[q2]; }
    else if (o < 276) { int q2 = o - 264, m = q2 >> 2, hh = q2 & 3; w = rm_w + (long)(hh * 3 + m) * 1024; bias = rm_b[hh * 3 + m]; }
    else if (o < 340) { int q2 = o - 276; w = wk_w + (long)q2 * 1024; bias = wk_b[q2]; }
    else if (o == 340){ w = ws_w; bias = ws_b[0]; }
    else if (o < 405) { int q2 = o - 341; w = ev_w + (long)q2 * 1024; bias = ev_b[q2]; }
    else if (o < 469) { int q2 = o - 405; w = wv_w + (long)q2 * 1024; bias = wv_b[q2]; }
    else if (o == 469){ w = ag_w; bias = ag_b[0]; }
    else              { w = wg_w; bias = wg_b[0]; }
    float wreg[16];
#pragma unroll
    for (int i = 0; i < 16; ++i) wreg[i] = w[lane + 64 * i];
#pragma unroll
    for (int bb = 0; bb < 8; ++bb) {
      float s = 0.f;
#pragma unroll
      for (int i = 0; i < 16; ++i) s += h_s[bb][lane + 64 * i] * wreg[i];
#pragma unroll
      for (int off = 32; off; off >>= 1) s += __shfl_xor(s, off);
      if (lane == 0) ws[OFF_PROJ + (long)(bbase + bb) * 512 + o] = s + bias;
    }
  }
}

// ===== shuffle reductions over half0's 128 values (2 syncs each) ===========
__device__ __forceinline__ float red128_max(float v, float* red, int tid) {
#pragma unroll
  for (int off = 32; off; off >>= 1) v = fmaxf(v, __shfl_xor(v, off));
  if (tid < 128 && (tid & 63) == 0) red[tid >> 6] = v;
  __syncthreads();
  float r = fmaxf(red[0], red[1]);
  __syncthreads();
  return r;
}
__device__ __forceinline__ float red128_sum(float v, float* red, int tid) {
#pragma unroll
  for (int off = 32; off; off >>= 1) v += __shfl_xor(v, off);
  if (tid < 128 && (tid & 63) == 0) red[tid >> 6] = v;
  __syncthreads();
  float r = red[0] + red[1];
  __syncthreads();
  return r;
}

// ===== memAB v2: shuffle sort/scan/reductions; mem+links in LDS ============
constexpr int SMEMF = 28744;   // floats (114,976 B)
__global__ __launch_bounds__(256) void memAB_kernel(int t, float* __restrict__ ws) {
  extern __shared__ float sm[];
  float* mem_s = sm;               // [128][65]  8320
  float* lk_s  = sm + 8320;        // [128][129] 16512
  float* red   = sm + 24832;       // 8
  float* wwl   = sm + 24840;       // 128
  float* pl    = sm + 24968;       // 128
  float* kwl   = sm + 25096;       // 64
  float* knl   = sm + 25160;       // 64
  float* dl    = sm + 25224;       // 64
  float* kl    = sm + 25288;       // 256
  float* rwold = sm + 25544;       // 512
  float* rwnew = sm + 26056;       // 512
  float* fpart = sm + 26568;       // 1024
  float* bpart = sm + 27592;       // 1024
  float* su    = sm + 28616;       // 128 (cross-wave sort exchange)
  int b = blockIdx.x, tid = threadIdx.x;
  int n = tid & 127, half = tid >> 7, lane = tid & 63;
  const float* pj = ws + OFF_PROJ + b * 512;
  float* u    = ws + OFF_U  + b * 128;
  float* wwp  = ws + OFF_WW + b * 128;
  float* pp   = ws + OFF_P  + b * 128;
  float* rwp  = ws + OFF_RW + b * 512;
  float* memp = ws + OFF_MEM + (long)b * 8192;
  float* lk   = ws + OFF_LINKS + (long)b * 16384;

  for (int i = tid; i < 8192; i += 256) mem_s[(i >> 6) * 65 + (i & 63)] = memp[i];
  for (int i = tid; i < 16384; i += 256) lk_s[(i >> 7) * 129 + (i & 127)] = lk[i];

  // ---- phase A scalars ----
  float uu = 0.f;
  if (half == 0) {
    float fg0 = sigm(pj[260]), fg1 = sigm(pj[261]), fg2 = sigm(pj[262]), fg3 = sigm(pj[263]);
    float r0 = rwp[n * 4], r1 = rwp[n * 4 + 1], r2 = rwp[n * 4 + 2], r3 = rwp[n * 4 + 3];
    rwold[n * 4] = r0; rwold[n * 4 + 1] = r1; rwold[n * 4 + 2] = r2; rwold[n * 4 + 3] = r3;
    float psi = expf(logf(1.f - fg0 * r0) + logf(1.f - fg1 * r1) +
                     logf(1.f - fg2 * r2) + logf(1.f - fg3 * r3));
    float u0 = u[n], wwo = wwp[n];
    uu = (u0 + wwo - u0 * wwo) * psi;
    u[n] = uu;
  }
  if (tid < 64) {
    kwl[tid] = pj[276 + tid];
    dl[tid] = sigm(pj[405 + tid]) - sigm(pj[341 + tid]);  // writev - erase
  }
  if (tid >= 128 && tid < 192) {
    int q = tid - 128;
#pragma unroll
    for (int h = 0; h < 4; ++h) kl[q * 4 + h] = pj[q * 4 + h];
  }
  __syncthreads();   // mem_s, lk_s, kwl, kl, rwold visible
  float kn2 = 0.f;
#pragma unroll
  for (int w = 0; w < 64; ++w) kn2 += kwl[w] * kwl[w];
  float kn = sqrtf(kn2);
  if (tid < 64) knl[tid] = kwl[tid] / kn;

  // ---- bitonic sort of uu across half0 (registers + shfl; 1 LDS exchange) --
  float v = uu;
  if (half == 0) {
#pragma unroll
    for (int k = 2; k <= 64; k <<= 1) {
#pragma unroll
      for (int j = k >> 1; j > 0; j >>= 1) {
        float other = __shfl_xor(v, j);
        bool up = ((n & k) == 0);
        bool high = (n & j) != 0;
        float mn = fminf(v, other), mx2 = fmaxf(v, other);
        v = (high == up) ? mx2 : mn;
      }
    }
    su[n] = v;
  }
  __syncthreads();   // also makes knl visible
  if (half == 0) {
    float other = su[n ^ 64];             // k=128, j=64 step (up for all n<128)
    v = ((n & 64) != 0) ? fmaxf(v, other) : fminf(v, other);
#pragma unroll
    for (int j = 32; j > 0; j >>= 1) {
      float other2 = __shfl_xor(v, j);
      bool high = (n & j) != 0;
      v = high ? fmaxf(v, other2) : fminf(v, other2);   // up==true for k=128
    }
  }
  // ---- inclusive scan of log(v) via shfl_up + cross-wave add --------------
  float lgv = 0.f;
  if (half == 0) {
    lgv = logf(v);
#pragma unroll
    for (int d = 1; d < 64; d <<= 1) {
      float t2 = __shfl_up(lgv, d);
      lgv = (lane >= d) ? lgv + t2 : lgv;
    }
  }
  if (tid == 63) red[0] = lgv;            // wave0 inclusive total
  __syncthreads();
  if (half == 0 && (tid >> 6) == 1) lgv += red[0];
  __syncthreads();
  // ---- write attention ----------------------------------------------------
  float mrow[64];
  float score = -3.4e38f, e = 0.f, wwn = 0.f, a_n = 0.f;
  if (half == 0) {
    a_n = (1.f - v) * expf(lgv - logf(v));
    float sq = 0.f;
#pragma unroll
    for (int w = 0; w < 64; ++w) { float m = mem_s[n * 65 + w]; mrow[w] = m; sq += m * m; }
    float den = sqrtf(sq) + EPSF;
#pragma unroll
    for (int w = 0; w < 64; ++w) mrow[w] = mrow[w] / den;
    float dot = 0.f;
#pragma unroll
    for (int w = 0; w < 64; ++w) dot += mrow[w] * knl[w];
    score = dot * oneplus_(pj[340]);
  }
  float mx = red128_max(score, red, tid);
  e = (half == 0) ? expf(score - mx) : 0.f;
  float esum = red128_sum(e, red, tid);
  if (half == 0) {
    float cw = e / esum;
    float ag = sigm(pj[469]), wg = sigm(pj[470]);
    wwn = wg * (ag * a_n + (1.f - ag) * cw);
    wwp[n] = wwn; wwl[n] = wwn;
  }
  float sumww = red128_sum((half == 0) ? wwn : 0.f, red, tid);
  if (half == 0) {
    float pn = (1.f - sumww) * pp[n] + wwn;
    pp[n] = pn; pl[n] = pn;
  }
  __syncthreads();   // wwl, pl visible
  if (half == 0) {
#pragma unroll
    for (int w = 0; w < 64; ++w) mem_s[n * 65 + w] = mrow[w] + wwn * dl[w];
  }
  // link update: thread (col=n, rows half*64..+63)
  {
    float wn = wwl[n], pcol = pl[n];
    int base = half * 64;
    for (int q = 0; q < 64; ++q) {
      int k2 = base + q;
      float lv = lk_s[k2 * 129 + n] * (1.f - (wwl[k2] + wn)) + wwl[k2] * pcol;
      lk_s[k2 * 129 + n] = (k2 == n) ? 0.f : lv;
    }
  }
  __syncthreads();   // mem write + links update done

  // ---- phase B ----
  if (half == 0) {
    float sq = 0.f;
#pragma unroll
    for (int w = 0; w < 64; ++w) { float m = mem_s[n * 65 + w]; mrow[w] = m; sq += m * m; }
    float den2 = sqrtf(sq) + EPSF;
#pragma unroll
    for (int w = 0; w < 64; ++w) { mrow[w] = mrow[w] / den2; mem_s[n * 65 + w] = mrow[w]; }
  }
  __syncthreads();   // final mem visible
  float cr_[4];
#pragma unroll
  for (int h = 0; h < 4; ++h) {
    float s3 = 0.f;
#pragma unroll
    for (int w = 0; w < 64; ++w) { float kv = kl[w * 4 + h]; s3 += kv * kv; }
    float knh = sqrtf(s3);
    float sc = -3.4e38f;
    if (half == 0) {
      float d2 = 0.f;
#pragma unroll
      for (int w = 0; w < 64; ++w) d2 += mrow[w] * (kl[w * 4 + h] / knh);
      sc = d2 * oneplus_(pj[256 + h]);
    }
    float mxh = red128_max(sc, red, tid);
    float eh = (half == 0) ? expf(sc - mxh) : 0.f;
    float ehs = red128_sum(eh, red, tid);
    cr_[h] = eh / ehs;
  }
  // f/b partials over half the rows each (LDS, conflict-free stride 129)
  {
    float f0 = 0, f1 = 0, f2 = 0, f3 = 0, b0 = 0, b1 = 0, b2 = 0, b3 = 0;
    int base = half * 64;
    for (int q = 0; q < 64; ++q) {
      int jj = base + q;
      float lrow = lk_s[n * 129 + jj];
      float lcol = lk_s[jj * 129 + n];
      float q0 = rwold[jj * 4], q1 = rwold[jj * 4 + 1], q2 = rwold[jj * 4 + 2], q3 = rwold[jj * 4 + 3];
      f0 += lrow * q0; f1 += lrow * q1; f2 += lrow * q2; f3 += lrow * q3;
      b0 += lcol * q0; b1 += lcol * q1; b2 += lcol * q2; b3 += lcol * q3;
    }
    int o = half * 512 + n * 4;
    fpart[o] = f0; fpart[o + 1] = f1; fpart[o + 2] = f2; fpart[o + 3] = f3;
    bpart[o] = b0; bpart[o + 1] = b1; bpart[o + 2] = b2; bpart[o + 3] = b3;
  }
  __syncthreads();
  if (half == 0) {
#pragma unroll
    for (int h = 0; h < 4; ++h) {
      float fv = fpart[n * 4 + h] + fpart[512 + n * 4 + h];
      float bv = bpart[n * 4 + h] + bpart[512 + n * 4 + h];
      float m0 = pj[264 + h], m1 = pj[264 + 4 + h], m2 = pj[264 + 8 + h];
      float mm = fmaxf(m0, fmaxf(m1, m2));
      float e0 = expf(m0 - mm), e1 = expf(m1 - mm), e2 = expf(m2 - mm);
      float inv = 1.f / (e0 + e1 + e2);
      float rwv = (e0 * inv) * bv + (e1 * inv) * cr_[h] + (e2 * inv) * fv;
      rwp[n * 4 + h] = rwv;
      rwnew[n * 4 + h] = rwv;
    }
  }
  __syncthreads();
  for (int i = tid; i < 8192; i += 256) memp[i] = mem_s[(i >> 6) * 65 + (i & 63)];
  for (int i = tid; i < 16384; i += 256) lk[i] = lk_s[(i >> 7) * 129 + (i & 127)];
  {
    int w2 = tid & 63, which = tid >> 6;
    float rv = 0.f;
    for (int jj = 0; jj < 128; ++jj) rv += mem_s[jj * 65 + w2] * rwnew[jj * 4 + which];
    ws[OFF_RV + (long)(t + 1) * 8192 + b * 256 + w2 * 4 + which] = rv;
  }
}

// ===== out_gemm v2: register-prefetch double buffer ========================
__global__ __launch_bounds__(256) void out_gemm(
    const float* __restrict__ ws, const float* __restrict__ Why_w,
    const float* __restrict__ Why_b, const float* __restrict__ Wry_w,
    float* __restrict__ out) {
  __shared__ float al[16 * 132];
  __shared__ float bl[16 * 132];
  const float* Hp  = ws + OFF_H + 32768;   // [2048][1024]
  const float* RVp = ws + OFF_RV + 8192;   // [2048][256]
  int tid = threadIdx.x;
  int tx = tid & 15, ty = tid >> 4;
  int col0 = blockIdx.x * 128, row0 = blockIdx.y * 128;
  float acc[8][8];
#pragma unroll
  for (int i = 0; i < 8; ++i)
#pragma unroll
    for (int j = 0; j < 8; ++j) acc[i][j] = 0.f;
  float pva[8], pvb[8];
  // prologue: prefetch tile 0 into registers
#pragma unroll
  for (int q = 0; q < 8; ++q) {
    int i2 = q * 256 + tid;
    int r = i2 >> 4, k = i2 & 15;
    int gk = k;
    pva[q] = (gk < 1024) ? Hp[(long)(row0 + r) * 1024 + gk]
                         : RVp[(long)(row0 + r) * 256 + gk - 1024];
    pvb[q] = (gk < 1024) ? Why_w[(long)(col0 + r) * 1024 + gk]
                         : Wry_w[(long)(col0 + r) * 256 + gk - 1024];
  }
  for (int kt = 0; kt < 80; ++kt) {
    __syncthreads();
#pragma unroll
    for (int q = 0; q < 8; ++q) {
      int i2 = q * 256 + tid;
      int r = i2 >> 4, k = i2 & 15;
      al[k * 132 + r] = pva[q];
      bl[k * 132 + r] = pvb[q];
    }
    __syncthreads();
    if (kt < 79) {
      int k0n = (kt + 1) * 16;
#pragma unroll
      for (int q = 0; q < 8; ++q) {
        int i2 = q * 256 + tid;
        int r = i2 >> 4, k = i2 & 15;
        int gk = k0n + k;
        pva[q] = (gk < 1024) ? Hp[(long)(row0 + r) * 1024 + gk]
                             : RVp[(long)(row0 + r) * 256 + gk - 1024];
        pvb[q] = (gk < 1024) ? Why_w[(long)(col0 + r) * 1024 + gk]
                             : Wry_w[(long)(col0 + r) * 256 + gk - 1024];
      }
    }
#pragma unroll
    for (int k = 0; k < 16; ++k) {
      float4 a0 = *(const float4*)&al[k * 132 + ty * 8];
      float4 a1 = *(const float4*)&al[k * 132 + ty * 8 + 4];
      float4 c0 = *(const float4*)&bl[k * 132 + tx * 4];
      float4 c1 = *(const float4*)&bl[k * 132 + 64 + tx * 4];
      float ar[8] = {a0.x, a0.y, a0.z, a0.w, a1.x, a1.y, a1.z, a1.w};
      float br[8] = {c0.x, c0.y, c0.z, c0.w, c1.x, c1.y, c1.z, c1.w};
#pragma unroll
      for (int i = 0; i < 8; ++i)
#pragma unroll
        for (int j = 0; j < 8; ++j) acc[i][j] += ar[i] * br[j];
    }
  }
  float4 bb0 = *(const float4*)&Why_b[col0 + tx * 4];
  float4 bb1 = *(const float4*)&Why_b[col0 + 64 + tx * 4];
  float bias[8] = {bb0.x, bb0.y, bb0.z, bb0.w, bb1.x, bb1.y, bb1.z, bb1.w};
#pragma unroll
  for (int i = 0; i < 8; ++i) {
    long r = row0 + ty * 8 + i;
    float* op0 = out + r * 16000 + col0 + tx * 4;
    float* op1 = out + r * 16000 + col0 + 64 + tx * 4;
    float4 o0 = {acc[i][0] + bias[0], acc[i][1] + bias[1], acc[i][2] + bias[2], acc[i][3] + bias[3]};
    float4 o1 = {acc[i][4] + bias[4], acc[i][5] + bias[5], acc[i][6] + bias[6], acc[i][7] + bias[7]};
    *(float4*)op0 = o0;
    *(float4*)op1 = o1;
  }
}

extern "C" void kernel_launch(void* const* d_in, const int* in_sizes, int n_in,
                              void* d_out, int out_size, void* d_ws, size_t ws_size,
                              hipStream_t stream) {
  const void* src_raw = d_in[0];
  const float* emb   = (const float*)d_in[1];
  const float* W_ih  = (const float*)d_in[2];
  const float* W_hh  = (const float*)d_in[3];
  const float* b_ih  = (const float*)d_in[4];
  const float* b_hh  = (const float*)d_in[5];
  const float* rk_w  = (const float*)d_in[6];
  const float* rk_b  = (const float*)d_in[7];
  const float* rs_w  = (const float*)d_in[8];
  const float* rs_b  = (const float*)d_in[9];
  const float* fg_w  = (const float*)d_in[10];
  const float* fg_b  = (const float*)d_in[11];
  const float* rm_w  = (const float*)d_in[12];
  const float* rm_b  = (const float*)d_in[13];
  const float* wk_w  = (const float*)d_in[14];
  const float* wk_b  = (const float*)d_in[15];
  const float* ws_w  = (const float*)d_in[16];
  const float* ws_b  = (const float*)d_in[17];
  const float* ev_w  = (const float*)d_in[18];
  const float* ev_b  = (const float*)d_in[19];
  const float* wv_w  = (const float*)d_in[20];
  const float* wv_b  = (const float*)d_in[21];
  const float* ag_w  = (const float*)d_in[22];
  const float* ag_b  = (const float*)d_in[23];
  const float* wg_w  = (const float*)d_in[24];
  const float* wg_b  = (const float*)d_in[25];
  const float* Why_w = (const float*)d_in[26];
  const float* Why_b = (const float*)d_in[27];
  const float* Wry_w = (const float*)d_in[28];
  float* ws = (float*)d_ws;
  float* out = (float*)d_out;

  src_decode<<<1, 256, 0, stream>>>(src_raw, ws);
  init_kernel<<<512, 256, 0, stream>>>(ws);
  const size_t smem_bytes = (size_t)SMEMF * sizeof(float);  // ~115 KB
  for (int t = 0; t < TN; ++t) {
    gates_kernel<<<512, 256, 0, stream>>>(t, emb, W_ih, W_hh, b_ih, b_hh, ws);
    proj_kernel<<<dim3(60, 4), 256, 0, stream>>>(t, ws, rk_w, rk_b, rs_w, rs_b, fg_w, fg_b,
                                                 rm_w, rm_b, wk_w, wk_b, ws_w, ws_b,
                                                 ev_w, ev_b, wv_w, wv_b, ag_w, ag_b, wg_w, wg_b);
    memAB_kernel<<<32, 256, smem_bytes, stream>>>(t, ws);
  }
  out_gemm<<<dim3(125, 16), 256, 0, stream>>>(ws, Why_w, Why_b, Wry_w, out);
}